// Round 2
// 396.656 us; speedup vs baseline: 1.0653x; 1.0653x over previous
//
#include <hip/hip_runtime.h>
#include <hip/hip_bf16.h>

#define B_   32
#define D_   128
#define N_   16384            // H*W
#define K_   32
#define NS   128              // n per sub-tile per block
#define XS_STRIDE 136         // elems per n-row of Xs (272B, 16B-aligned, bank-staggered)
#define AST_STRIDE 136        // bf16 units; 272B rows

// ---- workspace layout (floats) ----
#define WS_WBF  0             // bf16 W[32][128] = -2*scale*log2e*cw  (2048 floats)
#define WS_SC   2048          // scale[k]*log2e (32)
#define WS_C2S  2080          // scale'[k]*||c_k||^2 (32)
#define WS_EP   2112          // Ep[NB][32][128], then AsumP[NB][32] after

typedef __attribute__((ext_vector_type(8))) short bf16x8;
typedef __attribute__((ext_vector_type(4))) float f32x4;

static __device__ inline unsigned int pk2(float lo, float hi) {
    __hip_bfloat162 h = __float22bfloat162_rn(make_float2(lo, hi));
    unsigned int r;
    __builtin_memcpy(&r, &h, 4);
    return r;
}

static __device__ inline bf16x8 pack8v(f32x4 a, f32x4 b) {
    union { unsigned int u[4]; bf16x8 f; } r;
    r.u[0] = pk2(a[0], a[1]);
    r.u[1] = pk2(a[2], a[3]);
    r.u[2] = pk2(b[0], b[1]);
    r.u[3] = pk2(b[2], b[3]);
    return r.f;
}

__global__ void prep_kernel(const float* __restrict__ cw,
                            const float* __restrict__ scale,
                            float* __restrict__ ws) {
    const int k = blockIdx.x;     // 32 blocks x 64 lanes
    const int l = threadIdx.x;
    const float sc = scale[k] * 1.44269504088896f;   // fold log2e
    unsigned short* Wbf = (unsigned short*)(ws + WS_WBF);
    float s = 0.f;
#pragma unroll
    for (int i = 0; i < 2; ++i) {
        const int d = l + i * 64;
        const float v = cw[k * D_ + d];
        s += v * v;
        const float w = -2.f * sc * v;
        unsigned int u = __float_as_uint(w);
        u += 0x7fffu + ((u >> 16) & 1u);
        Wbf[k * D_ + d] = (unsigned short)(u >> 16);
    }
#pragma unroll
    for (int o = 32; o > 0; o >>= 1) s += __shfl_down(s, o, 64);
    if (l == 0) {
        ws[WS_SC  + k] = sc;
        ws[WS_C2S + k] = sc * s;
    }
}

// Single-pass main kernel:
//   stage:  X tile (128 d x 128 n) -> bf16 via coalesced float4 loads. Values land
//           BOTH in registers (exactly the phase-2 B-frags this lane needs) and in
//           LDS in a d-major layout Xs[n][d] (row stride 136 elems), written with
//           scalar ds_write_b16 (the transpose).
//   phase1: per-lane d-contiguous MFMA B-frags via plain 16B-aligned ds_read_b128
//           from Xs, x2 from bf16, in-register softmax -> AsT.
//   phase2: E += A^T . X with A from AsT (LDS) and X from the staged registers.
// X is fetched from HBM exactly once.
template<int NCHUNKT>
__global__ __launch_bounds__(256, 3) void main_kernel(
        const float* __restrict__ X,
        const float* __restrict__ ws_ro,
        float* __restrict__ AsumP,
        float* __restrict__ Ep)
{
    constexpr int CSZT  = N_ / NCHUNKT;
    constexpr int NSUBT = CSZT / NS;

    __shared__ __align__(16) unsigned short Xs[NS * XS_STRIDE];    // 34816 B
    __shared__ __align__(16) unsigned short AsT[K_ * AST_STRIDE];  // 8704 B

    const int t    = threadIdx.x;
    const int lane = t & 63;
    const int w    = t >> 6;          // wave 0..3
    const int mc   = lane & 15;
    const int q    = lane >> 4;

    const int blk   = blockIdx.x;
    const int b     = blk / NCHUNKT;
    const int chunk = blk % NCHUNKT;
    const int n0    = chunk * CSZT;

    const float* Xb = X + (size_t)b * ((size_t)D_ * N_);

    // ---- persistent codeword A-frags: W[k = kb*16+mc][d = kd*32 + q*8 + j] ----
    const unsigned short* Wbf = (const unsigned short*)(ws_ro + WS_WBF);
    bf16x8 wf[2][4];
#pragma unroll
    for (int kb = 0; kb < 2; ++kb)
#pragma unroll
        for (int kd = 0; kd < 4; ++kd)
            wf[kb][kd] = *(const bf16x8*)&Wbf[(kb * 16 + mc) * D_ + kd * 32 + q * 8];

    // per-lane softmax constants for k = kb*16 + q*4 + r
    float scr[2][4], c2r[2][4];
#pragma unroll
    for (int kb = 0; kb < 2; ++kb)
#pragma unroll
        for (int r = 0; r < 4; ++r) {
            scr[kb][r] = ws_ro[WS_SC  + kb * 16 + q * 4 + r];
            c2r[kb][r] = ws_ro[WS_C2S + kb * 16 + q * 4 + r];
        }

    bf16x8 ones;
#pragma unroll
    for (int i = 0; i < 8; ++i) ones[i] = (short)0x3F80;

    f32x4 accE[2][2] = {{{0.f,0.f,0.f,0.f},{0.f,0.f,0.f,0.f}},
                        {{0.f,0.f,0.f,0.f},{0.f,0.f,0.f,0.f}}};
    f32x4 accO[2]    = {{0.f,0.f,0.f,0.f},{0.f,0.f,0.f,0.f}};

    // staging source: this lane owns rows d = w*32+mc and d+16, cols q*8..q*8+7
    // of every 32-n group (exactly its phase-2 B-fragments).
    const float* xr0 = Xb + (size_t)(w * 32 + mc) * N_ + n0 + q * 8;
    const int dA = w * 32 + mc;

    for (int s = 0; s < NSUBT; ++s) {
        // ================= stage: global -> regs(bf16) + LDS (d-major) =================
        const float* xp = xr0 + s * NS;
        bf16x8 xf0[4], xf1[4];
#pragma unroll
        for (int ks = 0; ks < 4; ++ks) {
            const f32x4 a0 = *(const f32x4*)(xp + ks * 32);
            const f32x4 b0 = *(const f32x4*)(xp + ks * 32 + 4);
            const f32x4 a1 = *(const f32x4*)(xp + ks * 32 + (size_t)16 * N_);
            const f32x4 b1 = *(const f32x4*)(xp + ks * 32 + (size_t)16 * N_ + 4);
            xf0[ks] = pack8v(a0, b0);
            xf1[ks] = pack8v(a1, b1);
        }
#pragma unroll
        for (int ks = 0; ks < 4; ++ks) {
            union { bf16x8 f; unsigned int u[4]; } ua, ub;
            ua.f = xf0[ks];
            ub.f = xf1[ks];
            const int base = (ks * 32 + q * 8) * XS_STRIDE + dA;   // n-row * stride + d
#pragma unroll
            for (int j2 = 0; j2 < 4; ++j2) {
                Xs[base + (2*j2)   * XS_STRIDE]      = (unsigned short)(ua.u[j2]);
                Xs[base + (2*j2+1) * XS_STRIDE]      = (unsigned short)(ua.u[j2] >> 16);
                Xs[base + (2*j2)   * XS_STRIDE + 16] = (unsigned short)(ub.u[j2]);
                Xs[base + (2*j2+1) * XS_STRIDE + 16] = (unsigned short)(ub.u[j2] >> 16);
            }
        }
        __syncthreads();   // Xs tile complete

        // ================= phase 1: xc via MFMA + in-register softmax =================
#pragma unroll
        for (int cb = 0; cb < NS / 64; ++cb) {
            const int ntl  = (w * (NS / 64) + cb) * 16;    // local n of this col-block
            const int rowb = (ntl + mc) * XS_STRIDE;       // this lane's n-row in Xs

            union fr { bf16x8 f; unsigned int u[4]; } xb[4];
#pragma unroll
            for (int kd = 0; kd < 4; ++kd)
                xb[kd].f = *(const bf16x8*)&Xs[rowb + kd * 32 + q * 8];  // 16B-aligned

            // x2 from bf16 (error << tolerance; xc already carries bf16 rounding,
            // and the common-mode x2 error cancels across k up to the scale gap)
            float x2 = 0.f;
#pragma unroll
            for (int kd = 0; kd < 4; ++kd)
#pragma unroll
                for (int wd = 0; wd < 4; ++wd) {
                    const float lo = __uint_as_float(xb[kd].u[wd] << 16);
                    const float hi = __uint_as_float(xb[kd].u[wd] & 0xffff0000u);
                    x2 = fmaf(lo, lo, x2);
                    x2 = fmaf(hi, hi, x2);
                }

            f32x4 S0 = {0.f,0.f,0.f,0.f};
            f32x4 S1 = {0.f,0.f,0.f,0.f};
#pragma unroll
            for (int kd = 0; kd < 4; ++kd) {
                S0 = __builtin_amdgcn_mfma_f32_16x16x32_bf16(wf[0][kd], xb[kd].f, S0, 0, 0, 0);
                S1 = __builtin_amdgcn_mfma_f32_16x16x32_bf16(wf[1][kd], xb[kd].f, S1, 0, 0, 0);
            }

            // x2: lane covered 32 of 128 d; sum over the q-groups
            x2 += __shfl_xor(x2, 16, 64);
            x2 += __shfl_xor(x2, 32, 64);

            // sl[k] (already scaled by log2e) for k = {q*4+r, 16+q*4+r}
            float sl[8];
#pragma unroll
            for (int r = 0; r < 4; ++r) {
                sl[r]     = fmaf(scr[0][r], x2, S0[r] + c2r[0][r]);
                sl[4 + r] = fmaf(scr[1][r], x2, S1[r] + c2r[1][r]);
            }
            float m = sl[0];
#pragma unroll
            for (int i = 1; i < 8; ++i) m = fmaxf(m, sl[i]);
            m = fmaxf(m, __shfl_xor(m, 16, 64));
            m = fmaxf(m, __shfl_xor(m, 32, 64));
            float ssum = 0.f;
#pragma unroll
            for (int i = 0; i < 8; ++i) { sl[i] = exp2f(sl[i] - m); ssum += sl[i]; }
            ssum += __shfl_xor(ssum, 16, 64);
            ssum += __shfl_xor(ssum, 32, 64);
            const float inv = 1.f / ssum;

            const int col = ntl + mc;
#pragma unroll
            for (int r = 0; r < 4; ++r) {
                const unsigned int u = pk2(sl[r] * inv, sl[4 + r] * inv);
                AsT[(q * 4 + r) * AST_STRIDE + col]      = (unsigned short)u;
                AsT[(16 + q * 4 + r) * AST_STRIDE + col] = (unsigned short)(u >> 16);
            }
        }
        __syncthreads();   // AsT complete; all Xs readers done

        // ================= phase 2: E += A^T . X (X from staged registers) =================
#pragma unroll
        for (int ks = 0; ks < NS / 32; ++ks) {
            const int nl = ks * 32 + q * 8;
            const bf16x8 a0 = *(const bf16x8*)&AsT[mc * AST_STRIDE + nl];
            const bf16x8 a1 = *(const bf16x8*)&AsT[(16 + mc) * AST_STRIDE + nl];
            accE[0][0] = __builtin_amdgcn_mfma_f32_16x16x32_bf16(a0, xf0[ks], accE[0][0], 0, 0, 0);
            accE[0][1] = __builtin_amdgcn_mfma_f32_16x16x32_bf16(a0, xf1[ks], accE[0][1], 0, 0, 0);
            accE[1][0] = __builtin_amdgcn_mfma_f32_16x16x32_bf16(a1, xf0[ks], accE[1][0], 0, 0, 0);
            accE[1][1] = __builtin_amdgcn_mfma_f32_16x16x32_bf16(a1, xf1[ks], accE[1][1], 0, 0, 0);
            if (w == 0) {
                accO[0] = __builtin_amdgcn_mfma_f32_16x16x32_bf16(a0, ones, accO[0], 0, 0, 0);
                accO[1] = __builtin_amdgcn_mfma_f32_16x16x32_bf16(a1, ones, accO[1], 0, 0, 0);
            }
        }
        // no barrier here: next stage only writes Xs (all phase-1 readers passed the
        // barrier above) and next AsT writes are behind the next stage barrier.
    }

    // ---- epilogue: per-block partials ----
    float* EpB = Ep + (size_t)blk * (K_ * D_);
#pragma unroll
    for (int kh = 0; kh < 2; ++kh)
#pragma unroll
        for (int ds = 0; ds < 2; ++ds)
#pragma unroll
            for (int r = 0; r < 4; ++r) {
                const int k = kh * 16 + q * 4 + r;
                const int d = w * 32 + ds * 16 + mc;
                EpB[k * D_ + d] = accE[kh][ds][r];
            }
    if (w == 0 && mc == 0) {
#pragma unroll
        for (int kh = 0; kh < 2; ++kh)
#pragma unroll
            for (int r = 0; r < 4; ++r)
                AsumP[blk * K_ + kh * 16 + q * 4 + r] = accO[kh][r];
    }
}

template<int NCHUNKT>
__global__ void finalize_kernel(const float* __restrict__ cw,
                                const float* __restrict__ AsumP,
                                const float* __restrict__ Ep,
                                float* __restrict__ out)
{
    const int idx = blockIdx.x * 256 + threadIdx.x;   // 131072 outputs
    const int d = idx & 127;
    const int k = (idx >> 7) & 31;
    const int b = idx >> 12;
    float s = 0.f, asum = 0.f;
#pragma unroll
    for (int c = 0; c < NCHUNKT; ++c) {
        const int blk = b * NCHUNKT + c;
        s    += Ep[(size_t)blk * (K_ * D_) + k * D_ + d];
        asum += AsumP[blk * K_ + k];
    }
    out[idx] = s - asum * cw[k * D_ + d];
}

extern "C" void kernel_launch(void* const* d_in, const int* in_sizes, int n_in,
                              void* d_out, int out_size, void* d_ws, size_t ws_size,
                              hipStream_t stream) {
    const float* X     = (const float*)d_in[0];
    const float* cw    = (const float*)d_in[1];
    const float* scale = (const float*)d_in[2];
    float* out = (float*)d_out;
    float* ws  = (float*)d_ws;

    prep_kernel<<<K_, 64, 0, stream>>>(cw, scale, ws);

    const size_t need32 = (size_t)(WS_EP + 1024 * (K_ * D_) + 1024 * K_) * 4;
    if (ws_size >= need32) {
        float* Ep    = ws + WS_EP;
        float* AsumP = Ep + (size_t)1024 * (K_ * D_);
        main_kernel<32><<<B_ * 32, 256, 0, stream>>>(X, ws, AsumP, Ep);
        finalize_kernel<32><<<(B_ * K_ * D_) / 256, 256, 0, stream>>>(cw, AsumP, Ep, out);
    } else {
        float* Ep    = ws + WS_EP;
        float* AsumP = Ep + (size_t)512 * (K_ * D_);
        main_kernel<16><<<B_ * 16, 256, 0, stream>>>(X, ws, AsumP, Ep);
        finalize_kernel<16><<<(B_ * K_ * D_) / 256, 256, 0, stream>>>(cw, AsumP, Ep, out);
    }
}

// Round 4
// 370.281 us; speedup vs baseline: 1.1412x; 1.0712x over previous
//
#include <hip/hip_runtime.h>
#include <hip/hip_bf16.h>

#define B_   32
#define D_   128
#define N_   16384            // H*W
#define K_   32
#define NS   64               // n per sub-tile per block
#define XS_STRIDE 136         // elems per n-row of Xs (272B, 16B-aligned, bank-staggered)
#define AST_STRIDE 72         // bf16 units; 144B rows (16B-aligned)

// ---- workspace layout (floats) ----
#define WS_WBF  0             // bf16 W[32][128] = -2*scale*log2e*cw  (2048 floats)
#define WS_SC   2048          // scale[k]*log2e (32)
#define WS_C2S  2080          // scale'[k]*||c_k||^2 (32)
#define WS_EP   2112          // Ep[NB][32][128], then AsumP[NB][32] after

typedef __attribute__((ext_vector_type(8))) short bf16x8;
typedef __attribute__((ext_vector_type(4))) float f32x4;

static __device__ inline unsigned int pk2(float lo, float hi) {
    __hip_bfloat162 h = __float22bfloat162_rn(make_float2(lo, hi));
    unsigned int r;
    __builtin_memcpy(&r, &h, 4);
    return r;
}

static __device__ inline bf16x8 pack8v(f32x4 a, f32x4 b) {
    union { unsigned int u[4]; bf16x8 f; } r;
    r.u[0] = pk2(a[0], a[1]);
    r.u[1] = pk2(a[2], a[3]);
    r.u[2] = pk2(b[0], b[1]);
    r.u[3] = pk2(b[2], b[3]);
    return r.f;
}

__global__ void prep_kernel(const float* __restrict__ cw,
                            const float* __restrict__ scale,
                            float* __restrict__ ws) {
    const int k = blockIdx.x;     // 32 blocks x 64 lanes
    const int l = threadIdx.x;
    const float sc = scale[k] * 1.44269504088896f;   // fold log2e
    unsigned short* Wbf = (unsigned short*)(ws + WS_WBF);
    float s = 0.f;
#pragma unroll
    for (int i = 0; i < 2; ++i) {
        const int d = l + i * 64;
        const float v = cw[k * D_ + d];
        s += v * v;
        const float w = -2.f * sc * v;
        unsigned int u = __float_as_uint(w);
        u += 0x7fffu + ((u >> 16) & 1u);
        Wbf[k * D_ + d] = (unsigned short)(u >> 16);
    }
#pragma unroll
    for (int o = 32; o > 0; o >>= 1) s += __shfl_down(s, o, 64);
    if (l == 0) {
        ws[WS_SC  + k] = sc;
        ws[WS_C2S + k] = sc * s;
    }
}

// Single-pass main kernel, software-pipelined:
//   loads:  sub-tile s+1's 8 float4 global loads issue BEFORE sub-tile s is packed
//           (T14 async-STAGE) so HBM latency hides under phase1+phase2.
//   stage:  X tile (128 d x 64 n) -> bf16; values land BOTH in registers (exactly
//           the phase-2 B-frags this lane needs) and in LDS d-major, with each
//           n-row's 128-d line ROTATED by 16*((n>>3)&3) elems (mod 128) so the
//           scalar b16 transpose writes are bank-conflict-free (q-groups land on
//           disjoint bank octets). Reader applies the same row rotation.
//   phase1: d-contiguous MFMA B-frags via plain ds_read_b128, x2 from bf16,
//           in-register softmax -> AsT.
//   phase2: E += A^T . X with A from AsT (LDS) and X from the staged registers.
// X is fetched from HBM exactly once.
// __launch_bounds__(256,2): live state ~190 VGPR (64 ld dbuf + 32 wf + 24 acc +
// 16 xf + consts) — a min-3-waves/EU cap (170) would force scratch spills.
template<int NCHUNKT>
__global__ __launch_bounds__(256, 2) void main_kernel(
        const float* __restrict__ X,
        const float* __restrict__ ws_ro,
        float* __restrict__ AsumP,
        float* __restrict__ Ep)
{
    constexpr int CSZT  = N_ / NCHUNKT;
    constexpr int NSUBT = CSZT / NS;

    __shared__ __align__(16) unsigned short Xs[NS * XS_STRIDE];    // 17408 B
    __shared__ __align__(16) unsigned short AsT[K_ * AST_STRIDE];  //  4608 B

    const int t    = threadIdx.x;
    const int lane = t & 63;
    const int w    = t >> 6;          // wave 0..3
    const int mc   = lane & 15;
    const int q    = lane >> 4;

    const int blk   = blockIdx.x;
    const int b     = blk / NCHUNKT;
    const int chunk = blk % NCHUNKT;
    const int n0    = chunk * CSZT;

    const float* Xb = X + (size_t)b * ((size_t)D_ * N_);

    // ---- persistent codeword A-frags: W[k = kb*16+mc][d = kd*32 + q*8 + j] ----
    const unsigned short* Wbf = (const unsigned short*)(ws_ro + WS_WBF);
    bf16x8 wf[2][4];
#pragma unroll
    for (int kb = 0; kb < 2; ++kb)
#pragma unroll
        for (int kd = 0; kd < 4; ++kd)
            wf[kb][kd] = *(const bf16x8*)&Wbf[(kb * 16 + mc) * D_ + kd * 32 + q * 8];

    // per-lane softmax constants for k = kb*16 + q*4 + r
    float scr[2][4], c2r[2][4];
#pragma unroll
    for (int kb = 0; kb < 2; ++kb)
#pragma unroll
        for (int r = 0; r < 4; ++r) {
            scr[kb][r] = ws_ro[WS_SC  + kb * 16 + q * 4 + r];
            c2r[kb][r] = ws_ro[WS_C2S + kb * 16 + q * 4 + r];
        }

    bf16x8 ones;
#pragma unroll
    for (int i = 0; i < 8; ++i) ones[i] = (short)0x3F80;

    f32x4 accE[2][2] = {{{0.f,0.f,0.f,0.f},{0.f,0.f,0.f,0.f}},
                        {{0.f,0.f,0.f,0.f},{0.f,0.f,0.f,0.f}}};
    f32x4 accO[2]    = {{0.f,0.f,0.f,0.f},{0.f,0.f,0.f,0.f}};

    // staging source: this lane owns rows d = w*32+mc and d+16, cols q*8..q*8+7
    // of every 32-n group (exactly its phase-2 B-fragments).
    const float* xr0 = Xb + (size_t)(w * 32 + mc) * N_ + n0 + q * 8;
    const int dA = w * 32 + mc;

    auto do_loads = [&](f32x4 (&dst)[8], int sidx) {
        const float* xp = xr0 + sidx * NS;
#pragma unroll
        for (int ks = 0; ks < 2; ++ks) {
            dst[ks * 4 + 0] = *(const f32x4*)(xp + ks * 32);
            dst[ks * 4 + 1] = *(const f32x4*)(xp + ks * 32 + 4);
            dst[ks * 4 + 2] = *(const f32x4*)(xp + ks * 32 + (size_t)16 * N_);
            dst[ks * 4 + 3] = *(const f32x4*)(xp + ks * 32 + (size_t)16 * N_ + 4);
        }
    };

    f32x4 ld[2][8];
    do_loads(ld[0], 0);

#pragma unroll
    for (int s = 0; s < NSUBT; ++s) {
        // ---- issue next sub-tile's loads first (latency hides under phases) ----
        if (s + 1 < NSUBT) do_loads(ld[(s + 1) & 1], s + 1);

        // ================= stage: regs(bf16) + LDS (d-major, row-rotated) =============
        bf16x8 xf0[2], xf1[2];
#pragma unroll
        for (int ks = 0; ks < 2; ++ks) {
            xf0[ks] = pack8v(ld[s & 1][ks * 4 + 0], ld[s & 1][ks * 4 + 1]);
            xf1[ks] = pack8v(ld[s & 1][ks * 4 + 2], ld[s & 1][ks * 4 + 3]);
        }
#pragma unroll
        for (int ks = 0; ks < 2; ++ks) {
            union { bf16x8 f; unsigned int u[4]; } ua, ub;
            ua.f = xf0[ks];
            ub.f = xf1[ks];
            const int rbase = (ks * 32 + q * 8) * XS_STRIDE;   // row (n) base
            // row-rotation: rows here have (row>>3)&3 == q for all ks
            const int ca  = (dA      + (q << 4)) & 127;
            const int cb2 = (dA + 16 + (q << 4)) & 127;
#pragma unroll
            for (int j2 = 0; j2 < 4; ++j2) {
                Xs[rbase + (2*j2)   * XS_STRIDE + ca]  = (unsigned short)(ua.u[j2]);
                Xs[rbase + (2*j2+1) * XS_STRIDE + ca]  = (unsigned short)(ua.u[j2] >> 16);
                Xs[rbase + (2*j2)   * XS_STRIDE + cb2] = (unsigned short)(ub.u[j2]);
                Xs[rbase + (2*j2+1) * XS_STRIDE + cb2] = (unsigned short)(ub.u[j2] >> 16);
            }
        }
        __syncthreads();   // Xs tile complete

        // ================= phase 1: xc via MFMA + in-register softmax =================
        {
            const int ntl  = w * 16;                       // local n of this col-block
            const int row  = ntl + mc;                     // this lane's n-row
            const int rowb = row * XS_STRIDE;
            const int qn   = (row >> 3) & 3;               // row's rotation index

            union fr { bf16x8 f; unsigned int u[4]; } xb[4];
#pragma unroll
            for (int kd = 0; kd < 4; ++kd)
                xb[kd].f = *(const bf16x8*)&Xs[rowb + ((kd * 32 + q * 8 + (qn << 4)) & 127)];

            // x2 from bf16 (error << tolerance; xc already carries bf16 rounding,
            // and the common-mode x2 error cancels across k up to the scale gap)
            float x2 = 0.f;
#pragma unroll
            for (int kd = 0; kd < 4; ++kd)
#pragma unroll
                for (int wd = 0; wd < 4; ++wd) {
                    const float lo = __uint_as_float(xb[kd].u[wd] << 16);
                    const float hi = __uint_as_float(xb[kd].u[wd] & 0xffff0000u);
                    x2 = fmaf(lo, lo, x2);
                    x2 = fmaf(hi, hi, x2);
                }

            f32x4 S0 = {0.f,0.f,0.f,0.f};
            f32x4 S1 = {0.f,0.f,0.f,0.f};
#pragma unroll
            for (int kd = 0; kd < 4; ++kd) {
                S0 = __builtin_amdgcn_mfma_f32_16x16x32_bf16(wf[0][kd], xb[kd].f, S0, 0, 0, 0);
                S1 = __builtin_amdgcn_mfma_f32_16x16x32_bf16(wf[1][kd], xb[kd].f, S1, 0, 0, 0);
            }

            // x2: lane covered 32 of 128 d; sum over the q-groups
            x2 += __shfl_xor(x2, 16, 64);
            x2 += __shfl_xor(x2, 32, 64);

            // sl[k] (already scaled by log2e) for k = {q*4+r, 16+q*4+r}
            float sl[8];
#pragma unroll
            for (int r = 0; r < 4; ++r) {
                sl[r]     = fmaf(scr[0][r], x2, S0[r] + c2r[0][r]);
                sl[4 + r] = fmaf(scr[1][r], x2, S1[r] + c2r[1][r]);
            }
            float m = sl[0];
#pragma unroll
            for (int i = 1; i < 8; ++i) m = fmaxf(m, sl[i]);
            m = fmaxf(m, __shfl_xor(m, 16, 64));
            m = fmaxf(m, __shfl_xor(m, 32, 64));
            float ssum = 0.f;
#pragma unroll
            for (int i = 0; i < 8; ++i) { sl[i] = exp2f(sl[i] - m); ssum += sl[i]; }
            ssum += __shfl_xor(ssum, 16, 64);
            ssum += __shfl_xor(ssum, 32, 64);
            const float inv = 1.f / ssum;

            const int col = ntl + mc;
#pragma unroll
            for (int r = 0; r < 4; ++r) {
                const unsigned int u = pk2(sl[r] * inv, sl[4 + r] * inv);
                AsT[(q * 4 + r) * AST_STRIDE + col]      = (unsigned short)u;
                AsT[(16 + q * 4 + r) * AST_STRIDE + col] = (unsigned short)(u >> 16);
            }
        }
        __syncthreads();   // AsT complete; all Xs readers done

        // ================= phase 2: E += A^T . X (X from staged registers) =================
#pragma unroll
        for (int ks = 0; ks < 2; ++ks) {
            const int nl = ks * 32 + q * 8;
            const bf16x8 a0 = *(const bf16x8*)&AsT[mc * AST_STRIDE + nl];
            const bf16x8 a1 = *(const bf16x8*)&AsT[(16 + mc) * AST_STRIDE + nl];
            accE[0][0] = __builtin_amdgcn_mfma_f32_16x16x32_bf16(a0, xf0[ks], accE[0][0], 0, 0, 0);
            accE[0][1] = __builtin_amdgcn_mfma_f32_16x16x32_bf16(a0, xf1[ks], accE[0][1], 0, 0, 0);
            accE[1][0] = __builtin_amdgcn_mfma_f32_16x16x32_bf16(a1, xf0[ks], accE[1][0], 0, 0, 0);
            accE[1][1] = __builtin_amdgcn_mfma_f32_16x16x32_bf16(a1, xf1[ks], accE[1][1], 0, 0, 0);
            if (w == 0) {
                accO[0] = __builtin_amdgcn_mfma_f32_16x16x32_bf16(a0, ones, accO[0], 0, 0, 0);
                accO[1] = __builtin_amdgcn_mfma_f32_16x16x32_bf16(a1, ones, accO[1], 0, 0, 0);
            }
        }
        // no barrier here: next stage only writes Xs (all phase-1 readers passed the
        // barrier above) and next AsT writes are behind the next stage barrier.
    }

    // ---- epilogue: per-block partials ----
    float* EpB = Ep + (size_t)blk * (K_ * D_);
#pragma unroll
    for (int kh = 0; kh < 2; ++kh)
#pragma unroll
        for (int ds = 0; ds < 2; ++ds)
#pragma unroll
            for (int r = 0; r < 4; ++r) {
                const int k = kh * 16 + q * 4 + r;
                const int d = w * 32 + ds * 16 + mc;
                EpB[k * D_ + d] = accE[kh][ds][r];
            }
    if (w == 0 && mc == 0) {
#pragma unroll
        for (int kh = 0; kh < 2; ++kh)
#pragma unroll
            for (int r = 0; r < 4; ++r)
                AsumP[blk * K_ + kh * 16 + q * 4 + r] = accO[kh][r];
    }
}

template<int NCHUNKT>
__global__ void finalize_kernel(const float* __restrict__ cw,
                                const float* __restrict__ AsumP,
                                const float* __restrict__ Ep,
                                float* __restrict__ out)
{
    const int idx = blockIdx.x * 256 + threadIdx.x;   // 131072 outputs
    const int d = idx & 127;
    const int k = (idx >> 7) & 31;
    const int b = idx >> 12;
    float s = 0.f, asum = 0.f;
#pragma unroll
    for (int c = 0; c < NCHUNKT; ++c) {
        const int blk = b * NCHUNKT + c;
        s    += Ep[(size_t)blk * (K_ * D_) + k * D_ + d];
        asum += AsumP[blk * K_ + k];
    }
    out[idx] = s - asum * cw[k * D_ + d];
}

extern "C" void kernel_launch(void* const* d_in, const int* in_sizes, int n_in,
                              void* d_out, int out_size, void* d_ws, size_t ws_size,
                              hipStream_t stream) {
    const float* X     = (const float*)d_in[0];
    const float* cw    = (const float*)d_in[1];
    const float* scale = (const float*)d_in[2];
    float* out = (float*)d_out;
    float* ws  = (float*)d_ws;

    prep_kernel<<<K_, 64, 0, stream>>>(cw, scale, ws);

    const size_t need32 = (size_t)(WS_EP + 1024 * (K_ * D_) + 1024 * K_) * 4;
    if (ws_size >= need32) {
        float* Ep    = ws + WS_EP;
        float* AsumP = Ep + (size_t)1024 * (K_ * D_);
        main_kernel<32><<<B_ * 32, 256, 0, stream>>>(X, ws, AsumP, Ep);
        finalize_kernel<32><<<(B_ * K_ * D_) / 256, 256, 0, stream>>>(cw, AsumP, Ep, out);
    } else {
        float* Ep    = ws + WS_EP;
        float* AsumP = Ep + (size_t)512 * (K_ * D_);
        main_kernel<16><<<B_ * 16, 256, 0, stream>>>(X, ws, AsumP, Ep);
        finalize_kernel<16><<<(B_ * K_ * D_) / 256, 256, 0, stream>>>(cw, AsumP, Ep, out);
    }
}